// Round 3
// baseline (84.697 us; speedup 1.0000x reference)
//
#include <hip/hip_runtime.h>

// Chamfer via MFMA — R15: convoy-breaking on top of R14.
// d2 = psq + qsq - 2 p.q in ONE v_mfma_f32_32x32x16_bf16 per 32x32 tile
// (packing PROVEN R6-R12, absmax 0.0):
//   A k: {psqh,psql,-2ph(y,z,w),-2pl(y,z,w) | -2ph(y,z,w),1,1,0,0,0}
//   B k: {1,1,qh(y,z,w),qh(y,z,w) | ql(y,z,w),qsqh,qsql,0,0,0}
// R15 changes vs R14 (R14: 66.6 µs = fill 40.5 + chamfer ~21 + final ~2;
// loop pipe floors sum to ~5 µs -> ~16 µs of stall, theory: phase-locked
// convoys of the 16 identical waves after __syncthreads):
//  1. WAVE STAGGER: wave wv starts its row-tile sweep at pair-index
//     rotation rp=(wv&3)*4 (wrap mod 16). Same SET of tiles, different
//     ORDER -> fmin-exact (commutative/associative on finite data),
//     bitwise-identical partials; but waves on one SIMD now occupy
//     different loop phases -> lgkm waits / MFMA bursts / VALU folds
//     interleave across waves instead of convoying.
//  2. EXPLICIT A-PREFETCH: iteration i+1's 2x ds_read_b128 issue right
//     after the MFMAs, before the folds -> ~120cy LDS latency hides under
//     the folds instead of stalling the top of the next iteration.
//  3. s_setprio(1) around the MFMA cluster (T5) — stagger creates the
//     wave role-split that makes priority arbitration meaningful.
// Work split, partial layout, final kernel: IDENTICAL to R14 -> absmax
// 0.0 preserved. Non-atomic partials -> ws (atomicAdd herd +7 µs, R12).

typedef short bf16x8 __attribute__((ext_vector_type(8)));
typedef float f32x16 __attribute__((ext_vector_type(16)));

#define ONE_BF 0x3f80

__device__ __forceinline__ unsigned short f2bf(float x) {
    unsigned u = __float_as_uint(x);
    u += 0x7fffu + ((u >> 16) & 1u);          // round-to-nearest-even
    return (unsigned short)(u >> 16);
}
__device__ __forceinline__ float bf2f(unsigned short h) {
    return __uint_as_float(((unsigned)h) << 16);
}

__global__ __launch_bounds__(1024, 4) void chamfer_dir(
    const float4* __restrict__ P, const float4* __restrict__ Q,
    float* __restrict__ part)
{
    __shared__ short lAh[1024 * 8];   // A k-slots 0-7  (16 KB)
    __shared__ short lAl[1024 * 8];   // A k-slots 8-15 (16 KB)
    __shared__ short lB[1024 * 16];   // B interleaved [pt][half][8] (32 KB)
    // total 64 KB -> 1 block/CU with grid 256 = CU count

    const int blk   = blockIdx.x;      // 0..255
    const int batch = blk >> 1;        // 0..127
    const int dir   = blk & 1;         // 0: rows=P cols=Q; 1: swapped
    const int t     = threadIdx.x;     // 0..1023
    const int base  = batch << 10;

    const float4* __restrict__ ownb = (dir ? Q : P) + base;   // rows
    const float4* __restrict__ oppb = (dir ? P : Q) + base;   // cols

    // ---- Pack rows into LDS A-fragments: 1 pt/thread ----
    {
        float4 v = ownb[t];
        float psq = v.y * v.y + v.z * v.z + v.w * v.w;
        unsigned short psqh = f2bf(psq);
        unsigned short psql = f2bf(psq - bf2f(psqh));
        unsigned short yh = f2bf(v.y), zh = f2bf(v.z), wh = f2bf(v.w);
        unsigned short m2yh = f2bf(-2.0f * bf2f(yh));
        unsigned short m2zh = f2bf(-2.0f * bf2f(zh));
        unsigned short m2wh = f2bf(-2.0f * bf2f(wh));
        unsigned short m2yl = f2bf(-2.0f * (v.y - bf2f(yh)));
        unsigned short m2zl = f2bf(-2.0f * (v.z - bf2f(zh)));
        unsigned short m2wl = f2bf(-2.0f * (v.w - bf2f(wh)));
        bf16x8 ah = { (short)psqh, (short)psql, (short)m2yh, (short)m2zh,
                      (short)m2wh, (short)m2yl, (short)m2zl, (short)m2wl };
        bf16x8 al = { (short)m2yh, (short)m2zh, (short)m2wh,
                      (short)ONE_BF, (short)ONE_BF, 0, 0, 0 };
        *(bf16x8*)&lAh[t * 8] = ah;
        *(bf16x8*)&lAl[t * 8] = al;
    }
    // ---- Pack ALL 1024 cols into LDS B-fragments: 1 pt/thread ----
    {
        float4 v = oppb[t];
        float qsq = v.y * v.y + v.z * v.z + v.w * v.w;
        unsigned short qsqh = f2bf(qsq);
        unsigned short qsql = f2bf(qsq - bf2f(qsqh));
        unsigned short yh = f2bf(v.y), zh = f2bf(v.z), wh = f2bf(v.w);
        unsigned short yl = f2bf(v.y - bf2f(yh));
        unsigned short zl = f2bf(v.z - bf2f(zh));
        unsigned short wl = f2bf(v.w - bf2f(wh));
        bf16x8 bh = { (short)ONE_BF, (short)ONE_BF, (short)yh, (short)zh,
                      (short)wh, (short)yh, (short)zh, (short)wh };
        bf16x8 bl = { (short)yl, (short)zl, (short)wl,
                      (short)qsqh, (short)qsql, 0, 0, 0 };
        *(bf16x8*)&lB[t * 16]     = bh;
        *(bf16x8*)&lB[t * 16 + 8] = bl;
    }
    __syncthreads();

    const int lane = t & 63;
    const int half = lane >> 5;    // k-half: 0 -> slots 0-7, 1 -> 8-15
    const int l31  = lane & 31;
    const int wv   = t >> 6;       // 0..15

    // Byte-addressed A base: per-lane half select + lane row offset.
    const char* __restrict__ aB =
        (const char*)(half ? lAl : lAh) + l31 * 16;

    // Two col-tiles per wave: c0 = wv*2, c0+1
    const int c0 = wv << 1;
    bf16x8 bf0 = *(const bf16x8*)&lB[((((c0)     << 5) + l31) * 2 + half) * 8];
    bf16x8 bf1 = *(const bf16x8*)&lB[((((c0 + 1) << 5) + l31) * 2 + half) * 8];

    f32x16 zf;
#pragma unroll
    for (int j = 0; j < 16; ++j) zf[j] = 0.0f;

    f32x16 acc0, acc1;
#pragma unroll
    for (int j = 0; j < 16; ++j) { acc0[j] = 3.4e38f; acc1[j] = 3.4e38f; }

    // Stagger: wave starts at rotated pair-index rp (mod 16). Same tile
    // SET, different order -> bitwise-identical mins, desynced pipes.
    const int rp = (wv & 3) << 2;              // 0,4,8,12

    // Prologue: load pair rp.
    bf16x8 af0 = *(const bf16x8*)(aB + ((rp << 10)));
    bf16x8 af1 = *(const bf16x8*)(aB + ((rp << 10) + 512));

#pragma unroll
    for (int i = 0; i < 16; ++i) {
        __builtin_amdgcn_s_setprio(1);
        f32x16 ca = __builtin_amdgcn_mfma_f32_32x32x16_bf16(af0, bf0, zf, 0, 0, 0);
        f32x16 cb = __builtin_amdgcn_mfma_f32_32x32x16_bf16(af1, bf0, zf, 0, 0, 0);
        f32x16 cc = __builtin_amdgcn_mfma_f32_32x32x16_bf16(af0, bf1, zf, 0, 0, 0);
        f32x16 cd = __builtin_amdgcn_mfma_f32_32x32x16_bf16(af1, bf1, zf, 0, 0, 0);
        __builtin_amdgcn_s_setprio(0);
        // Prefetch next pair's A-fragments BEFORE the folds: LDS latency
        // hides under the 32 v_min3 below.
        if (i < 15) {
            const int prn = ((i + 1) + rp) & 15;
            af0 = *(const bf16x8*)(aB + (prn << 10));
            af1 = *(const bf16x8*)(aB + ((prn << 10) + 512));
        }
#pragma unroll
        for (int j = 0; j < 16; ++j)
            acc0[j] = fminf(fminf(ca[j], cb[j]), acc0[j]);   // v_min3_f32
#pragma unroll
        for (int j = 0; j < 16; ++j)
            acc1[j] = fminf(fminf(cc[j], cd[j]), acc1[j]);
    }

    // Epilogue: 16->1 tree, cross-half shfl, sqrt, wave-sum, wave partial.
    // (identical arithmetic + order to R14 -> bitwise-same partials)
    float m0 = acc0[0], m1 = acc1[0];
#pragma unroll
    for (int j = 1; j < 16; ++j) { m0 = fminf(m0, acc0[j]); m1 = fminf(m1, acc1[j]); }
    m0 = fminf(m0, __shfl_xor(m0, 32, 64));
    m1 = fminf(m1, __shfl_xor(m1, 32, 64));

    float s = 0.0f;
    if (half == 0)
        s = sqrtf(fmaxf(m0, 0.0f) + 1e-12f) + sqrtf(fmaxf(m1, 0.0f) + 1e-12f);
#pragma unroll
    for (int off = 32; off; off >>= 1) s += __shfl_down(s, off, 64);
    if (lane == 0) part[(blk << 4) + wv] = s;   // == batch*32 + dir*16 + w
}

__global__ __launch_bounds__(256) void chamfer_final(
    const float* __restrict__ part, float* __restrict__ out)
{
    __shared__ float ws[4];
    const int t = threadIdx.x;
    // Same linear 4096-partial array + same summation order as R14.
    float s = 0.0f;
#pragma unroll
    for (int k = 0; k < 4; ++k) {
        const float4 w = *(const float4*)&part[(t + (k << 8)) << 2];
        float bk = ((w.x + w.y) + w.z) + w.w;
        s = (k == 0) ? bk : (s + bk);
    }
#pragma unroll
    for (int off = 32; off; off >>= 1) s += __shfl_down(s, off, 64);
    if ((t & 63) == 0) ws[t >> 6] = s;
    __syncthreads();
    if (t == 0) out[0] = ws[0] + ws[1] + ws[2] + ws[3];
}

extern "C" void kernel_launch(void* const* d_in, const int* in_sizes, int n_in,
                              void* d_out, int out_size, void* d_ws, size_t ws_size,
                              hipStream_t stream) {
    const float4* P = (const float4*)d_in[0];
    const float4* Q = (const float4*)d_in[1];
    float* out  = (float*)d_out;
    float* part = (float*)d_ws;   // 4096 per-wave partials (16 KB)

    chamfer_dir<<<dim3(128 * 2), dim3(1024), 0, stream>>>(P, Q, part);
    chamfer_final<<<dim3(1), dim3(256), 0, stream>>>(part, out);
}

// Round 4
// 65.517 us; speedup vs baseline: 1.2928x; 1.2928x over previous
//
#include <hip/hip_runtime.h>

// Chamfer via MFMA — R16: R14 + one-deep SSA A-prefetch (no setprio, no
// stagger — R15's −18µs regression was diagnosed as VGPR spill from the
// setprio-pinned 4-transient cluster + runtime-rotated addressing).
// d2 = psq + qsq - 2 p.q in ONE v_mfma_f32_32x32x16_bf16 per 32x32 tile
// (packing PROVEN R6-R12, absmax 0.0):
//   A k: {psqh,psql,-2ph(y,z,w),-2pl(y,z,w) | -2ph(y,z,w),1,1,0,0,0}
//   B k: {1,1,qh(y,z,w),qh(y,z,w) | ql(y,z,w),qsqh,qsql,0,0,0}
// R16 changes vs R14 (66.6 µs):
//  1. A-reads software-pipelined ONE iteration ahead into a SEPARATE
//     register set (afA/afB, parity-selected at COMPILE TIME in the
//     fully-unrolled loop): next pair's 2x ds_read_b128 issue before this
//     pair's MFMAs -> ~120cy LDS latency hides under MFMA+folds; no WAR
//     hazard, no runtime address math (all offsets are immediates).
//  2. Folds sit between the two MFMA pairs -> peak transients 32 VGPR
//     (not 64): live ~112 <= 128 cap of the 1024-thr block. No spill.
//  3. Iteration-0 peel: acc = fmin(ca,cb) directly. fmin(x,3.4e38)==x for
//     all finite x -> bitwise-identical result, saves the init movs.
// Pack, grid, epilogue order, partial layout, final kernel: IDENTICAL to
// R14 -> absmax 0.0 preserved. Non-atomic partials -> ws (atomicAdd herd
// +7 µs, R12).

typedef short bf16x8 __attribute__((ext_vector_type(8)));
typedef float f32x16 __attribute__((ext_vector_type(16)));

#define ONE_BF 0x3f80

__device__ __forceinline__ unsigned short f2bf(float x) {
    unsigned u = __float_as_uint(x);
    u += 0x7fffu + ((u >> 16) & 1u);          // round-to-nearest-even
    return (unsigned short)(u >> 16);
}
__device__ __forceinline__ float bf2f(unsigned short h) {
    return __uint_as_float(((unsigned)h) << 16);
}

__global__ __launch_bounds__(1024, 4) void chamfer_dir(
    const float4* __restrict__ P, const float4* __restrict__ Q,
    float* __restrict__ part)
{
    __shared__ short lAh[1024 * 8];   // A k-slots 0-7  (16 KB)
    __shared__ short lAl[1024 * 8];   // A k-slots 8-15 (16 KB)
    __shared__ short lB[1024 * 16];   // B interleaved [pt][half][8] (32 KB)
    // total 64 KB -> 1 block/CU with grid 256 = CU count

    const int blk   = blockIdx.x;      // 0..255
    const int batch = blk >> 1;        // 0..127
    const int dir   = blk & 1;         // 0: rows=P cols=Q; 1: swapped
    const int t     = threadIdx.x;     // 0..1023
    const int base  = batch << 10;

    const float4* __restrict__ ownb = (dir ? Q : P) + base;   // rows
    const float4* __restrict__ oppb = (dir ? P : Q) + base;   // cols

    // ---- Pack rows into LDS A-fragments: 1 pt/thread ----
    {
        float4 v = ownb[t];
        float psq = v.y * v.y + v.z * v.z + v.w * v.w;
        unsigned short psqh = f2bf(psq);
        unsigned short psql = f2bf(psq - bf2f(psqh));
        unsigned short yh = f2bf(v.y), zh = f2bf(v.z), wh = f2bf(v.w);
        unsigned short m2yh = f2bf(-2.0f * bf2f(yh));
        unsigned short m2zh = f2bf(-2.0f * bf2f(zh));
        unsigned short m2wh = f2bf(-2.0f * bf2f(wh));
        unsigned short m2yl = f2bf(-2.0f * (v.y - bf2f(yh)));
        unsigned short m2zl = f2bf(-2.0f * (v.z - bf2f(zh)));
        unsigned short m2wl = f2bf(-2.0f * (v.w - bf2f(wh)));
        bf16x8 ah = { (short)psqh, (short)psql, (short)m2yh, (short)m2zh,
                      (short)m2wh, (short)m2yl, (short)m2zl, (short)m2wl };
        bf16x8 al = { (short)m2yh, (short)m2zh, (short)m2wh,
                      (short)ONE_BF, (short)ONE_BF, 0, 0, 0 };
        *(bf16x8*)&lAh[t * 8] = ah;
        *(bf16x8*)&lAl[t * 8] = al;
    }
    // ---- Pack ALL 1024 cols into LDS B-fragments: 1 pt/thread ----
    {
        float4 v = oppb[t];
        float qsq = v.y * v.y + v.z * v.z + v.w * v.w;
        unsigned short qsqh = f2bf(qsq);
        unsigned short qsql = f2bf(qsq - bf2f(qsqh));
        unsigned short yh = f2bf(v.y), zh = f2bf(v.z), wh = f2bf(v.w);
        unsigned short yl = f2bf(v.y - bf2f(yh));
        unsigned short zl = f2bf(v.z - bf2f(zh));
        unsigned short wl = f2bf(v.w - bf2f(wh));
        bf16x8 bh = { (short)ONE_BF, (short)ONE_BF, (short)yh, (short)zh,
                      (short)wh, (short)yh, (short)zh, (short)wh };
        bf16x8 bl = { (short)yl, (short)zl, (short)wl,
                      (short)qsqh, (short)qsql, 0, 0, 0 };
        *(bf16x8*)&lB[t * 16]     = bh;
        *(bf16x8*)&lB[t * 16 + 8] = bl;
    }
    __syncthreads();

    const int lane = t & 63;
    const int half = lane >> 5;    // k-half: 0 -> slots 0-7, 1 -> 8-15
    const int l31  = lane & 31;
    const int wv   = t >> 6;       // 0..15

    // Byte-addressed A base; all loop offsets are compile-time immediates.
    // Row-tile pair i lives at aB + i*1024 (+512 for the odd tile).
    const char* __restrict__ aB =
        (const char*)(half ? lAl : lAh) + l31 * 16;

    // Two col-tiles per wave: c0 = wv*2, c0+1
    const int c0 = wv << 1;
    bf16x8 bf0 = *(const bf16x8*)&lB[((((c0)     << 5) + l31) * 2 + half) * 8];
    bf16x8 bf1 = *(const bf16x8*)&lB[((((c0 + 1) << 5) + l31) * 2 + half) * 8];

    f32x16 zf;
#pragma unroll
    for (int j = 0; j < 16; ++j) zf[j] = 0.0f;

    f32x16 acc0, acc1;

    // Prologue: load pair 0 into set A.
    bf16x8 afA0 = *(const bf16x8*)(aB);
    bf16x8 afA1 = *(const bf16x8*)(aB + 512);
    bf16x8 afB0 = afA0, afB1 = afA1;   // dead init (silences -Wuninitialized)

#pragma unroll
    for (int i = 0; i < 16; ++i) {
        // Compile-time parity register-set select (loop fully unrolled).
        bf16x8 f0, f1;
        if ((i & 1) == 0) { f0 = afA0; f1 = afA1; }
        else              { f0 = afB0; f1 = afB1; }
        // Prefetch pair i+1 into the OTHER set before this pair's MFMAs:
        // ds latency hides under the MFMAs + folds below.
        if (i < 15) {
            if ((i & 1) == 0) {
                afB0 = *(const bf16x8*)(aB + ((i + 1) << 10));
                afB1 = *(const bf16x8*)(aB + ((i + 1) << 10) + 512);
            } else {
                afA0 = *(const bf16x8*)(aB + ((i + 1) << 10));
                afA1 = *(const bf16x8*)(aB + ((i + 1) << 10) + 512);
            }
        }
        f32x16 ca = __builtin_amdgcn_mfma_f32_32x32x16_bf16(f0, bf0, zf, 0, 0, 0);
        f32x16 cb = __builtin_amdgcn_mfma_f32_32x32x16_bf16(f1, bf0, zf, 0, 0, 0);
        if (i == 0) {
#pragma unroll
            for (int j = 0; j < 16; ++j) acc0[j] = fminf(ca[j], cb[j]);
        } else {
#pragma unroll
            for (int j = 0; j < 16; ++j)
                acc0[j] = fminf(fminf(ca[j], cb[j]), acc0[j]);   // v_min3_f32
        }
        f32x16 cc = __builtin_amdgcn_mfma_f32_32x32x16_bf16(f0, bf1, zf, 0, 0, 0);
        f32x16 cd = __builtin_amdgcn_mfma_f32_32x32x16_bf16(f1, bf1, zf, 0, 0, 0);
        if (i == 0) {
#pragma unroll
            for (int j = 0; j < 16; ++j) acc1[j] = fminf(cc[j], cd[j]);
        } else {
#pragma unroll
            for (int j = 0; j < 16; ++j)
                acc1[j] = fminf(fminf(cc[j], cd[j]), acc1[j]);
        }
    }

    // Epilogue: 16->1 tree, cross-half shfl, sqrt, wave-sum, wave partial.
    // (identical arithmetic + order to R14 -> bitwise-same partials)
    float m0 = acc0[0], m1 = acc1[0];
#pragma unroll
    for (int j = 1; j < 16; ++j) { m0 = fminf(m0, acc0[j]); m1 = fminf(m1, acc1[j]); }
    m0 = fminf(m0, __shfl_xor(m0, 32, 64));
    m1 = fminf(m1, __shfl_xor(m1, 32, 64));

    float s = 0.0f;
    if (half == 0)
        s = sqrtf(fmaxf(m0, 0.0f) + 1e-12f) + sqrtf(fmaxf(m1, 0.0f) + 1e-12f);
#pragma unroll
    for (int off = 32; off; off >>= 1) s += __shfl_down(s, off, 64);
    if (lane == 0) part[(blk << 4) + wv] = s;   // == batch*32 + dir*16 + w
}

__global__ __launch_bounds__(256) void chamfer_final(
    const float* __restrict__ part, float* __restrict__ out)
{
    __shared__ float ws[4];
    const int t = threadIdx.x;
    // Same linear 4096-partial array + same summation order as R14.
    float s = 0.0f;
#pragma unroll
    for (int k = 0; k < 4; ++k) {
        const float4 w = *(const float4*)&part[(t + (k << 8)) << 2];
        float bk = ((w.x + w.y) + w.z) + w.w;
        s = (k == 0) ? bk : (s + bk);
    }
#pragma unroll
    for (int off = 32; off; off >>= 1) s += __shfl_down(s, off, 64);
    if ((t & 63) == 0) ws[t >> 6] = s;
    __syncthreads();
    if (t == 0) out[0] = ws[0] + ws[1] + ws[2] + ws[3];
}

extern "C" void kernel_launch(void* const* d_in, const int* in_sizes, int n_in,
                              void* d_out, int out_size, void* d_ws, size_t ws_size,
                              hipStream_t stream) {
    const float4* P = (const float4*)d_in[0];
    const float4* Q = (const float4*)d_in[1];
    float* out  = (float*)d_out;
    float* part = (float*)d_ws;   // 4096 per-wave partials (16 KB)

    chamfer_dir<<<dim3(128 * 2), dim3(1024), 0, stream>>>(P, Q, part);
    chamfer_final<<<dim3(1), dim3(256), 0, stream>>>(part, out);
}